// Round 15
// baseline (447.380 us; speedup 1.0000x reference)
//
#include <hip/hip_runtime.h>

#define N_NODES 50000
#define INC 300
#define KP1 320      // padded K for layer-1 GEMM (bf16)
#define HID 512
#define OUTC 512
#define MTILES 391   // ceil(50000/128)
#define MCHUNK 49    // ceil(391/8) m-tiles per XCD

typedef unsigned short u16;
typedef __bf16 bf16;
typedef bf16 bf16x8 __attribute__((ext_vector_type(8)));
typedef float f32x4 __attribute__((ext_vector_type(4)));
typedef float f32x2 __attribute__((ext_vector_type(2)));
typedef unsigned u32x4 __attribute__((ext_vector_type(4)));

__device__ inline u16 f32_to_bf16(float f) {
  unsigned u = __float_as_uint(f);
  u += 0x7FFFu + ((u >> 16) & 1u);   // round-to-nearest-even
  return (u16)(u >> 16);
}

__device__ inline float bf_lo(unsigned u) { return __uint_as_float(u << 16); }
__device__ inline float bf_hi(unsigned u) { return __uint_as_float(u & 0xFFFF0000u); }

// counted wait + hard scheduling fence (rule #18)
#define WAITV(N)                                            \
  do {                                                      \
    asm volatile("s_waitcnt vmcnt(" #N ")" ::: "memory");   \
    __builtin_amdgcn_sched_barrier(0);                      \
  } while (0)

#define WAITLGKM0()                                         \
  do {                                                      \
    asm volatile("s_waitcnt lgkmcnt(0)" ::: "memory");      \
    __builtin_amdgcn_sched_barrier(0);                      \
  } while (0)

#define SBAR()                                              \
  do {                                                      \
    __builtin_amdgcn_s_barrier();                           \
    __builtin_amdgcn_sched_barrier(0);                      \
  } while (0)

__device__ __forceinline__ void acc8(float a[8], u32x4 q) {
#pragma unroll
  for (int t = 0; t < 4; ++t) {
    a[2 * t]     += bf_lo(q[t]);
    a[2 * t + 1] += bf_hi(q[t]);
  }
}

// ---- rolling-pipeline row gather: steady-state 8 dwordx4 loads in flight ----
template <int RU>
__device__ __forceinline__ void gather_row(
    const u32x4* __restrict__ src, const int* __restrict__ csr_col,
    int s, int cnt, int lane, int lanec, float a[8]) {
  const u32x4* base = src + lanec;
  for (int off = 0; off < cnt; off += 64) {
    int cnt2 = min(64, cnt - off);
    int myc = csr_col[s + off + min(lane, cnt2 - 1)];
    int ngr = (cnt2 + 3) >> 2;

    auto issue = [&](u32x4 (&q)[4], int g) {
#pragma unroll
      for (int k = 0; k < 4; ++k) {
        int c = __shfl(myc, min(4 * g + k, cnt2 - 1), 64);
        const u32x4* ap = base + (size_t)c * RU;
        asm volatile("global_load_dwordx4 %0, %1, off" : "=v"(q[k]) : "v"(ap));
      }
    };
    auto cons = [&](u32x4 (&q)[4], int g) {
#pragma unroll
      for (int k = 0; k < 4; ++k)
        if (4 * g + k < cnt2) acc8(a, q[k]);
    };

    u32x4 qa[4], qb[4];
    issue(qa, 0);
    int g = 0;
    while (g + 2 < ngr) {
      issue(qb, g + 1); WAITV(4); cons(qa, g);
      issue(qa, g + 2); WAITV(4); cons(qb, g + 1);
      g += 2;
    }
    if (g + 1 < ngr) {
      issue(qb, g + 1); WAITV(4); cons(qa, g);
      WAITV(0); cons(qb, g + 1);
    } else {
      WAITV(0); cons(qa, g);
    }
  }
}

// ---------------- fused setup: convx | convw1 | convw2 | hist ----------------
#define CX_BLK 31250                  // N_NODES*160/256
#define CW1_BLK 640                   // HID*KP1/256
#define CW2_BLK 1024                  // OUTC*HID/256
__global__ __launch_bounds__(256) void fused_setup(
    const float* __restrict__ x, unsigned* __restrict__ xb,
    const float* __restrict__ W1, u16* __restrict__ W1b,
    const float* __restrict__ W2, u16* __restrict__ W2b,
    const int* __restrict__ erow, int* __restrict__ deg, int E) {
  int bid = blockIdx.x;
  if (bid < CX_BLK) {
    int i = bid * 256 + threadIdx.x;                  // over N*160 u32 slots
    int r = i / 160, j = i - r * 160;
    unsigned out = 0;
    if (2 * j < INC) {
      f32x2 v = __builtin_nontemporal_load((const f32x2*)(x + (size_t)r * INC + 2 * j));
      out = (unsigned)f32_to_bf16(v.x) | ((unsigned)f32_to_bf16(v.y) << 16);
    }
    xb[i] = out;
  } else if (bid < CX_BLK + CW1_BLK) {
    int i = (bid - CX_BLK) * 256 + threadIdx.x;       // over HID*KP1
    int r = i / KP1, k = i - r * KP1;
    W1b[i] = (k < INC) ? f32_to_bf16(W1[(size_t)r * INC + k]) : (u16)0;
  } else if (bid < CX_BLK + CW1_BLK + CW2_BLK) {
    int i = (bid - CX_BLK - CW1_BLK) * 256 + threadIdx.x;   // over OUTC*HID
    W2b[i] = f32_to_bf16(W2[i]);
  } else {
    int i = (bid - CX_BLK - CW1_BLK - CW2_BLK) * 256 + threadIdx.x;
    if (i < E) atomicAdd(&deg[erow[i]], 1);
  }
}

// ---------------- CSR scan/scatter ----------------
__global__ __launch_bounds__(1024) void k_scan(const int* __restrict__ deg,
                                               int* __restrict__ rowstart) {
  __shared__ int part[1024];
  int tid = threadIdx.x;
  const int ch = (N_NODES + 1023) / 1024;
  int lo = tid * ch;
  int hi = lo + ch;
  if (lo > N_NODES) lo = N_NODES;
  if (hi > N_NODES) hi = N_NODES;
  int s = 0;
  for (int i = lo; i < hi; ++i) s += deg[i];
  part[tid] = s;
  __syncthreads();
  for (int off = 1; off < 1024; off <<= 1) {
    int v = (tid >= off) ? part[tid - off] : 0;
    __syncthreads();
    part[tid] += v;
    __syncthreads();
  }
  int run = (tid > 0) ? part[tid - 1] : 0;
  for (int i = lo; i < hi; ++i) { rowstart[i] = run; run += deg[i]; }
  if (tid == 1023) rowstart[N_NODES] = part[1023];
}

__global__ void k_scatter(const int* __restrict__ erow, const int* __restrict__ ecol,
                          int E, const int* __restrict__ rowstart,
                          int* __restrict__ cursor, int* __restrict__ csr_col) {
  int i = blockIdx.x * blockDim.x + threadIdx.x;
  if (i < E) {
    int r = erow[i];
    int p = atomicAdd(&cursor[r], 1);
    csr_col[rowstart[r] + p] = ecol[i];
  }
}

// ---------------- SpMM layer 1: ax = (A @ xb) * 1/deg ------------------------
__global__ __launch_bounds__(256, 8) void spmm_x(
    const u32x4* __restrict__ xb, const int* __restrict__ csr_col,
    const int* __restrict__ rs, u32x4* __restrict__ ax) {
  int r = blockIdx.x * 4 + (threadIdx.x >> 6);
  int lane = threadIdx.x & 63;
  int lanec = min(lane, 39);               // row = 160 u32 = 40 x u32x4
  int s = rs[r], e = rs[r + 1];
  float a[8];
#pragma unroll
  for (int k = 0; k < 8; ++k) a[k] = 0.f;
  gather_row<40>(xb, csr_col, s, e - s, lane, lanec, a);
  float inv = 1.0f / (float)max(e - s, 1);
  u32x4 o;
#pragma unroll
  for (int j = 0; j < 4; ++j) {
    unsigned lo = f32_to_bf16(a[2 * j] * inv);
    unsigned hi = f32_to_bf16(a[2 * j + 1] * inv);
    o[j] = lo | (hi << 16);
  }
  if (lane < 40) ax[(size_t)r * 40 + lane] = o;
}

// ---- SpMM layer 2 fused: out = normalize( (A @ g) * 1/deg + b2 ) -------------
__global__ __launch_bounds__(256, 8) void spmm_norm(
    const u32x4* __restrict__ g, const int* __restrict__ csr_col,
    const int* __restrict__ rs, const float* __restrict__ b2,
    float* __restrict__ out) {
  int r = blockIdx.x * 4 + (threadIdx.x >> 6);
  int lane = threadIdx.x & 63;
  int s = rs[r], e = rs[r + 1];
  float a[8];
#pragma unroll
  for (int k = 0; k < 8; ++k) a[k] = 0.f;
  gather_row<64>(g, csr_col, s, e - s, lane, lane, a);
  float inv = 1.0f / (float)max(e - s, 1);
  f32x4 bv0 = *(const f32x4*)(b2 + lane * 8);
  f32x4 bv1 = *(const f32x4*)(b2 + lane * 8 + 4);
  float v[8];
  v[0] = a[0] * inv + bv0.x; v[1] = a[1] * inv + bv0.y;
  v[2] = a[2] * inv + bv0.z; v[3] = a[3] * inv + bv0.w;
  v[4] = a[4] * inv + bv1.x; v[5] = a[5] * inv + bv1.y;
  v[6] = a[6] * inv + bv1.z; v[7] = a[7] * inv + bv1.w;
  float ss = 0.f;
#pragma unroll
  for (int k = 0; k < 8; ++k) ss += v[k] * v[k];
#pragma unroll
  for (int off = 32; off > 0; off >>= 1) ss += __shfl_xor(ss, off, 64);
  float innrm = 1.0f / fmaxf(sqrtf(ss), 1e-12f);
  f32x4 o0 = {v[0] * innrm, v[1] * innrm, v[2] * innrm, v[3] * innrm};
  f32x4 o1 = {v[4] * innrm, v[5] * innrm, v[6] * innrm, v[7] * innrm};
  float* op = out + (size_t)r * OUTC + lane * 8;
  __builtin_nontemporal_store(o0, (f32x4*)op);
  __builtin_nontemporal_store(o1, (f32x4*)(op + 4));
}

// ---- bf16 MFMA GEMM: reg-staged K-major-subtiled LDS (bank-conflict-free) ----
// LDS layout per tile: [s=row>>4][q=kslot][r16=row&15][8 bf16]
//   write banks: 4*srow%32 (2-way, free);  read banks: 4*fr%32 (2-way, free)
// vs old [row][32] layout whose ds_read_b128 was an 8-way conflict (2.94x).
// Pipeline: 2 LDS bufs; regs hold tile t+1 in flight; per iter:
//   ds_read(buf cur) -> WAITV(0) -> ds_write t+1 (buf cur^1) -> issue loads t+2
//   -> lgkmcnt(0) -> MFMA -> s_barrier.
// WAR-safe: buf cur^1's readers (iter t-1) sealed by iter t-1's end barrier.
template <int KPAD, bool RELU, bool HAS_BIAS>
__global__ __launch_bounds__(256) void gemm_nt(
    const u16* __restrict__ A, const u16* __restrict__ B,
    const float* __restrict__ bias, u16* __restrict__ Cout, int M) {
  __shared__ __align__(16) u16 SH[16384];   // 2 bufs x (A 8KB + B 8KB) = 32KB
  const int bid = blockIdx.x;
  const int xcd = bid & 7;
  const int j = bid >> 3;
  const int mt = xcd * MCHUNK + (j >> 2);
  if (mt >= MTILES) return;
  const int m0 = mt * 128;
  const int n0 = (j & 3) * 128;

  const int tid = threadIdx.x;
  const int wid = tid >> 6;
  const int lane = tid & 63;

  const int srow = lane >> 2;               // staging row-within-16
  const int scol = (lane & 3) * 8;          // staging k-slot (global u16 col)
  const int wm = (wid >> 1) * 64;
  const int wn = (wid & 1) * 64;
  const int fr = lane & 15;
  const int q = lane >> 4;

  // clamped global row bases (columns advance by k0 only)
  const int gmA0 = min(m0 + wid * 32 + srow, M - 1);
  const int gmA1 = min(m0 + wid * 32 + 16 + srow, M - 1);
  const int gnB0 = n0 + wid * 32 + srow;
  const int gnB1 = gnB0 + 16;
  const u16* baseA0 = A + (size_t)gmA0 * KPAD + scol;
  const u16* baseA1 = A + (size_t)gmA1 * KPAD + scol;
  const u16* baseB0 = B + (size_t)gnB0 * KPAD + scol;
  const u16* baseB1 = B + (size_t)gnB1 * KPAD + scol;

  // LDS u16 offsets
  auto As = [&](int buf) { return SH + buf * 8192; };
  auto Bs = [&](int buf) { return SH + buf * 8192 + 4096; };
  const int wA0 = (wid * 2 + 0) * 512 + (lane & 3) * 128 + srow * 8;
  const int wA1 = (wid * 2 + 1) * 512 + (lane & 3) * 128 + srow * 8;

  u32x4 ra0, ra1, rb0, rb1;                 // in-flight tile regs
  auto GLOAD = [&](int k0) {
    const u16* pa0 = baseA0 + k0;
    const u16* pa1 = baseA1 + k0;
    const u16* pb0 = baseB0 + k0;
    const u16* pb1 = baseB1 + k0;
    asm volatile("global_load_dwordx4 %0, %1, off" : "=v"(ra0) : "v"(pa0));
    asm volatile("global_load_dwordx4 %0, %1, off" : "=v"(ra1) : "v"(pa1));
    asm volatile("global_load_dwordx4 %0, %1, off" : "=v"(rb0) : "v"(pb0));
    asm volatile("global_load_dwordx4 %0, %1, off" : "=v"(rb1) : "v"(pb1));
  };
  auto DSWRITE = [&](int buf) {
    *(u32x4*)(As(buf) + wA0) = ra0;
    *(u32x4*)(As(buf) + wA1) = ra1;
    *(u32x4*)(Bs(buf) + wA0) = rb0;
    *(u32x4*)(Bs(buf) + wA1) = rb1;
  };

  f32x4 acc[4][4];
#pragma unroll
  for (int i = 0; i < 4; ++i)
#pragma unroll
    for (int jj = 0; jj < 4; ++jj) acc[i][jj] = (f32x4){0.f, 0.f, 0.f, 0.f};

  constexpr int NT = KPAD / 32;
  const int sA = (wid >> 1) * 4;            // A subtile base = wm/16
  const int sB = (wid & 1) * 4;             // B subtile base = wn/16

  // prologue: tile0 -> buf0, tile1 in regs
  GLOAD(0);
  WAITV(0);
  DSWRITE(0);
  GLOAD(32);
  WAITLGKM0();
  SBAR();

  for (int t = 0; t < NT; ++t) {
    const int cur = t & 1;
    const u16* Ab = As(cur);
    const u16* Bb = Bs(cur);
    bf16x8 af[4], bfr[4];
#pragma unroll
    for (int r = 0; r < 4; ++r)
      af[r] = *(const bf16x8*)(Ab + (sA + r) * 512 + q * 128 + fr * 8);
#pragma unroll
    for (int c = 0; c < 4; ++c)
      bfr[c] = *(const bf16x8*)(Bb + (sB + c) * 512 + q * 128 + fr * 8);
    if (t + 1 < NT) {
      WAITV(0);                 // tile t+1 regs landed
      DSWRITE(cur ^ 1);         // readers of buf cur^1 sealed at iter t-1
      if (t + 2 < NT) GLOAD((t + 2) * 32);
    }
    WAITLGKM0();                // frags read + ds_writes done
#pragma unroll
    for (int r = 0; r < 4; ++r)
#pragma unroll
      for (int c = 0; c < 4; ++c)
        acc[r][c] = __builtin_amdgcn_mfma_f32_16x16x32_bf16(af[r], bfr[c],
                                                            acc[r][c], 0, 0, 0);
    SBAR();                     // seals buf-cur reads + buf-cur^1 writes
  }

  // ---- epilogue: C tile via LDS overlay (32KB), coalesced 16B stores ---------
  u16* CT = SH;
  const int cr = q * 4;
#pragma unroll
  for (int c = 0; c < 4; ++c) {
    int col = wn + c * 16 + fr;
    float bv = HAS_BIAS ? bias[n0 + col] : 0.f;
#pragma unroll
    for (int r = 0; r < 4; ++r) {
#pragma unroll
      for (int jj = 0; jj < 4; ++jj) {
        float v = acc[r][c][jj] + bv;
        if (RELU) v = fmaxf(v, 0.f);
        CT[(wm + r * 16 + cr + jj) * 128 + col] = f32_to_bf16(v);
      }
    }
  }
  __syncthreads();
#pragma unroll
  for (int ps = 0; ps < 8; ++ps) {
    int rl = ps * 16 + (tid >> 4);
    int gm = m0 + rl;
    bf16x8 w = *(const bf16x8*)(CT + rl * 128 + (tid & 15) * 8);
    if (gm < M)
      *(bf16x8*)(Cout + (size_t)gm * OUTC + n0 + (tid & 15) * 8) = w;
  }
}

extern "C" void kernel_launch(void* const* d_in, const int* in_sizes, int n_in,
                              void* d_out, int out_size, void* d_ws,
                              size_t ws_size, hipStream_t stream) {
  const float* x  = (const float*)d_in[0];
  const int* erow = (const int*)d_in[1];
  const int* ecol = (const int*)d_in[2];
  const float* W1 = (const float*)d_in[4];
  const float* b1 = (const float*)d_in[5];
  const float* W2 = (const float*)d_in[6];
  const float* b2 = (const float*)d_in[7];
  const int E = in_sizes[1];

  char* p = (char*)d_ws;
  auto carve = [&](size_t bytes) {
    char* q = p;
    p += (bytes + 255) & ~(size_t)255;
    return q;
  };
  unsigned* xb = (unsigned*)carve((size_t)N_NODES * 160 * 4);  // 32 MB bf16 x
  unsigned* ax = (unsigned*)carve((size_t)N_NODES * 160 * 4);  // 32 MB
  unsigned* h  = (unsigned*)carve((size_t)N_NODES * 256 * 4);  // 51.2 MB
  unsigned* g2 = (unsigned*)carve((size_t)N_NODES * 256 * 4);  // 51.2 MB
  u16* W1b = (u16*)carve((size_t)HID * KP1 * 2);
  u16* W2b = (u16*)carve((size_t)OUTC * HID * 2);
  int* deg  = (int*)carve((size_t)N_NODES * 4);
  int* rs   = (int*)carve((size_t)(N_NODES + 1) * 4);
  int* cur  = (int*)carve((size_t)N_NODES * 4);
  int* csr_col = (int*)carve((size_t)E * 4);

  (void)hipMemsetAsync(deg, 0, (size_t)N_NODES * 4, stream);
  (void)hipMemsetAsync(cur, 0, (size_t)N_NODES * 4, stream);

  int eb = (E + 255) / 256;
  fused_setup<<<CX_BLK + CW1_BLK + CW2_BLK + eb, 256, 0, stream>>>(
      x, xb, W1, W1b, W2, W2b, erow, deg, E);
  k_scan<<<1, 1024, 0, stream>>>(deg, rs);
  k_scatter<<<eb, 256, 0, stream>>>(erow, ecol, E, rs, cur, csr_col);

  const int GEMM_GRID = 8 * MCHUNK * 4;   // 1568
  // layer 1: h = relu((A @ x) @ W1^T + b1)
  spmm_x<<<N_NODES / 4, 256, 0, stream>>>((const u32x4*)xb, csr_col, rs, (u32x4*)ax);
  gemm_nt<KP1, true, true><<<GEMM_GRID, 256, 0, stream>>>(
      (const u16*)ax, W1b, b1, (u16*)h, N_NODES);

  // layer 2: out = normalize(A @ (h @ W2^T) + b2)
  gemm_nt<HID, false, false><<<GEMM_GRID, 256, 0, stream>>>(
      (const u16*)h, W2b, nullptr, (u16*)g2, N_NODES);
  spmm_norm<<<N_NODES / 4, 256, 0, stream>>>((const u32x4*)g2, csr_col, rs, b2, (float*)d_out);
}

// Round 16
// 433.288 us; speedup vs baseline: 1.0325x; 1.0325x over previous
//
#include <hip/hip_runtime.h>

#define N_NODES 50000
#define INC 300
#define KP1 320      // padded K for layer-1 GEMM (bf16)
#define HID 512
#define OUTC 512
#define MTILES 391   // ceil(50000/128)
#define MCHUNK 49    // ceil(391/8) m-tiles per XCD

typedef unsigned short u16;
typedef __bf16 bf16;
typedef bf16 bf16x8 __attribute__((ext_vector_type(8)));
typedef float f32x4 __attribute__((ext_vector_type(4)));
typedef float f32x2 __attribute__((ext_vector_type(2)));
typedef unsigned u32x4 __attribute__((ext_vector_type(4)));

__device__ inline u16 f32_to_bf16(float f) {
  unsigned u = __float_as_uint(f);
  u += 0x7FFFu + ((u >> 16) & 1u);   // round-to-nearest-even
  return (u16)(u >> 16);
}

__device__ inline float bf_lo(unsigned u) { return __uint_as_float(u << 16); }
__device__ inline float bf_hi(unsigned u) { return __uint_as_float(u & 0xFFFF0000u); }

__device__ inline void gload_lds16(const void* g, void* l) {
  __builtin_amdgcn_global_load_lds(
      (const __attribute__((address_space(1))) void*)g,
      (__attribute__((address_space(3))) void*)l, 16, 0, 0);
}

// counted wait + hard scheduling fence (rule #18)
#define WAITV(N)                                            \
  do {                                                      \
    asm volatile("s_waitcnt vmcnt(" #N ")" ::: "memory");   \
    __builtin_amdgcn_sched_barrier(0);                      \
  } while (0)

__device__ __forceinline__ void acc8(float a[8], u32x4 q) {
#pragma unroll
  for (int t = 0; t < 4; ++t) {
    a[2 * t]     += bf_lo(q[t]);
    a[2 * t + 1] += bf_hi(q[t]);
  }
}

// ---- rolling-pipeline row gather: steady-state 8 dwordx4 loads in flight ----
template <int RU>
__device__ __forceinline__ void gather_row(
    const u32x4* __restrict__ src, const int* __restrict__ csr_col,
    int s, int cnt, int lane, int lanec, float a[8]) {
  const u32x4* base = src + lanec;
  for (int off = 0; off < cnt; off += 64) {
    int cnt2 = min(64, cnt - off);
    int myc = csr_col[s + off + min(lane, cnt2 - 1)];
    int ngr = (cnt2 + 3) >> 2;

    auto issue = [&](u32x4 (&q)[4], int g) {
#pragma unroll
      for (int k = 0; k < 4; ++k) {
        int c = __shfl(myc, min(4 * g + k, cnt2 - 1), 64);
        const u32x4* ap = base + (size_t)c * RU;
        asm volatile("global_load_dwordx4 %0, %1, off" : "=v"(q[k]) : "v"(ap));
      }
    };
    auto cons = [&](u32x4 (&q)[4], int g) {
#pragma unroll
      for (int k = 0; k < 4; ++k)
        if (4 * g + k < cnt2) acc8(a, q[k]);
    };

    u32x4 qa[4], qb[4];
    issue(qa, 0);
    int g = 0;
    while (g + 2 < ngr) {
      issue(qb, g + 1); WAITV(4); cons(qa, g);
      issue(qa, g + 2); WAITV(4); cons(qb, g + 1);
      g += 2;
    }
    if (g + 1 < ngr) {
      issue(qb, g + 1); WAITV(4); cons(qa, g);
      WAITV(0); cons(qb, g + 1);
    } else {
      WAITV(0); cons(qa, g);
    }
  }
}

// ---------------- fused setup: convx | convw1 | convw2 | hist ----------------
#define CX_BLK 31250                  // N_NODES*160/256
#define CW1_BLK 640                   // HID*KP1/256
#define CW2_BLK 1024                  // OUTC*HID/256
__global__ __launch_bounds__(256) void fused_setup(
    const float* __restrict__ x, unsigned* __restrict__ xb,
    const float* __restrict__ W1, u16* __restrict__ W1b,
    const float* __restrict__ W2, u16* __restrict__ W2b,
    const int* __restrict__ erow, int* __restrict__ deg, int E) {
  int bid = blockIdx.x;
  if (bid < CX_BLK) {
    int i = bid * 256 + threadIdx.x;                  // over N*160 u32 slots
    int r = i / 160, j = i - r * 160;
    unsigned out = 0;
    if (2 * j < INC) {
      f32x2 v = __builtin_nontemporal_load((const f32x2*)(x + (size_t)r * INC + 2 * j));
      out = (unsigned)f32_to_bf16(v.x) | ((unsigned)f32_to_bf16(v.y) << 16);
    }
    xb[i] = out;
  } else if (bid < CX_BLK + CW1_BLK) {
    int i = (bid - CX_BLK) * 256 + threadIdx.x;       // over HID*KP1
    int r = i / KP1, k = i - r * KP1;
    W1b[i] = (k < INC) ? f32_to_bf16(W1[(size_t)r * INC + k]) : (u16)0;
  } else if (bid < CX_BLK + CW1_BLK + CW2_BLK) {
    int i = (bid - CX_BLK - CW1_BLK) * 256 + threadIdx.x;   // over OUTC*HID
    W2b[i] = f32_to_bf16(W2[i]);
  } else {
    int i = (bid - CX_BLK - CW1_BLK - CW2_BLK) * 256 + threadIdx.x;
    if (i < E) atomicAdd(&deg[erow[i]], 1);
  }
}

// ---------------- CSR scan/scatter ----------------
__global__ __launch_bounds__(1024) void k_scan(const int* __restrict__ deg,
                                               int* __restrict__ rowstart) {
  __shared__ int part[1024];
  int tid = threadIdx.x;
  const int ch = (N_NODES + 1023) / 1024;
  int lo = tid * ch;
  int hi = lo + ch;
  if (lo > N_NODES) lo = N_NODES;
  if (hi > N_NODES) hi = N_NODES;
  int s = 0;
  for (int i = lo; i < hi; ++i) s += deg[i];
  part[tid] = s;
  __syncthreads();
  for (int off = 1; off < 1024; off <<= 1) {
    int v = (tid >= off) ? part[tid - off] : 0;
    __syncthreads();
    part[tid] += v;
    __syncthreads();
  }
  int run = (tid > 0) ? part[tid - 1] : 0;
  for (int i = lo; i < hi; ++i) { rowstart[i] = run; run += deg[i]; }
  if (tid == 1023) rowstart[N_NODES] = part[1023];
}

__global__ void k_scatter(const int* __restrict__ erow, const int* __restrict__ ecol,
                          int E, const int* __restrict__ rowstart,
                          int* __restrict__ cursor, int* __restrict__ csr_col) {
  int i = blockIdx.x * blockDim.x + threadIdx.x;
  if (i < E) {
    int r = erow[i];
    int p = atomicAdd(&cursor[r], 1);
    csr_col[rowstart[r] + p] = ecol[i];
  }
}

// ---------------- SpMM layer 1: ax = (A @ xb) * 1/deg ------------------------
__global__ __launch_bounds__(256, 8) void spmm_x(
    const u32x4* __restrict__ xb, const int* __restrict__ csr_col,
    const int* __restrict__ rs, u32x4* __restrict__ ax) {
  int r = blockIdx.x * 4 + (threadIdx.x >> 6);
  int lane = threadIdx.x & 63;
  int lanec = min(lane, 39);               // row = 160 u32 = 40 x u32x4
  int s = rs[r], e = rs[r + 1];
  float a[8];
#pragma unroll
  for (int k = 0; k < 8; ++k) a[k] = 0.f;
  gather_row<40>(xb, csr_col, s, e - s, lane, lanec, a);
  float inv = 1.0f / (float)max(e - s, 1);
  u32x4 o;
#pragma unroll
  for (int j = 0; j < 4; ++j) {
    unsigned lo = f32_to_bf16(a[2 * j] * inv);
    unsigned hi = f32_to_bf16(a[2 * j + 1] * inv);
    o[j] = lo | (hi << 16);
  }
  if (lane < 40) ax[(size_t)r * 40 + lane] = o;
}

// ---- SpMM layer 2 fused: out = normalize( (A @ g) * 1/deg + b2 ) -------------
__global__ __launch_bounds__(256, 8) void spmm_norm(
    const u32x4* __restrict__ g, const int* __restrict__ csr_col,
    const int* __restrict__ rs, const float* __restrict__ b2,
    float* __restrict__ out) {
  int r = blockIdx.x * 4 + (threadIdx.x >> 6);
  int lane = threadIdx.x & 63;
  int s = rs[r], e = rs[r + 1];
  float a[8];
#pragma unroll
  for (int k = 0; k < 8; ++k) a[k] = 0.f;
  gather_row<64>(g, csr_col, s, e - s, lane, lane, a);
  float inv = 1.0f / (float)max(e - s, 1);
  f32x4 bv0 = *(const f32x4*)(b2 + lane * 8);
  f32x4 bv1 = *(const f32x4*)(b2 + lane * 8 + 4);
  float v[8];
  v[0] = a[0] * inv + bv0.x; v[1] = a[1] * inv + bv0.y;
  v[2] = a[2] * inv + bv0.z; v[3] = a[3] * inv + bv0.w;
  v[4] = a[4] * inv + bv1.x; v[5] = a[5] * inv + bv1.y;
  v[6] = a[6] * inv + bv1.z; v[7] = a[7] * inv + bv1.w;
  float ss = 0.f;
#pragma unroll
  for (int k = 0; k < 8; ++k) ss += v[k] * v[k];
#pragma unroll
  for (int off = 32; off > 0; off >>= 1) ss += __shfl_xor(ss, off, 64);
  float innrm = 1.0f / fmaxf(sqrtf(ss), 1e-12f);
  f32x4 o0 = {v[0] * innrm, v[1] * innrm, v[2] * innrm, v[3] * innrm};
  f32x4 o1 = {v[4] * innrm, v[5] * innrm, v[6] * innrm, v[7] * innrm};
  float* op = out + (size_t)r * OUTC + lane * 8;
  __builtin_nontemporal_store(o0, (f32x4*)op);
  __builtin_nontemporal_store(o1, (f32x4*)(op + 4));
}

// ---- bf16 MFMA GEMM: R14's proven 3-buffer counted-vmcnt gload_lds loop +
//      T2 XOR-swizzle (write side via pre-swizzled per-lane GLOBAL source,
//      linear LDS dest — m173-verified pattern; read side in ds_read addr).
//      Involution: stored slot s holds global slot s^f(row), f=(row>>1)&3.
//      Read banks drop from 8 lanes/bank-group to the 2-way minimum.
template <int KPAD, bool RELU, bool HAS_BIAS>
__global__ __launch_bounds__(256) void gemm_nt(
    const u16* __restrict__ A, const u16* __restrict__ B,
    const float* __restrict__ bias, u16* __restrict__ Cout, int M) {
  extern __shared__ __align__(16) u16 SH[];   // 48KB: 3x(A 8KB + B 8KB)
  const int bid = blockIdx.x;
  const int xcd = bid & 7;
  const int j = bid >> 3;
  const int mt = xcd * MCHUNK + (j >> 2);
  if (mt >= MTILES) return;
  const int m0 = mt * 128;
  const int n0 = (j & 3) * 128;

  const int tid = threadIdx.x;
  const int wid = tid >> 6;
  const int lane = tid & 63;

  const int srow = lane >> 2;
  // write-side swizzle: lane's linear LDS slot (lane&3) receives global slot
  // (lane&3) ^ f(row),  f(row) = (srow>>1)&3 = (lane>>3)&3
  const int scol = (((lane & 3) ^ ((lane >> 3) & 3)) * 8);
  const int wm = (wid >> 1) * 64;
  const int wn = (wid & 1) * 64;
  const int fr = lane & 15;
  // read-side: global slot q lives at stored slot q ^ ((fr>>1)&3)
  const int fswz = (((lane >> 4) ^ ((fr >> 1) & 3)) * 8);

  auto As = [&](int buf) { return SH + buf * 4096; };
  auto Bs = [&](int buf) { return SH + 12288 + buf * 4096; };

  auto STAGE = [&](int buf, int k0) {       // 4 gload_lds per thread
#pragma unroll
    for (int i = 0; i < 2; ++i) {
      int ar = wid * 32 + i * 16;
      int gm = m0 + ar + srow;
      if (gm >= M) gm = M - 1;
      gload_lds16(A + (size_t)gm * KPAD + k0 + scol, As(buf) + ar * 32);
      int gn = n0 + ar + srow;
      gload_lds16(B + (size_t)gn * KPAD + k0 + scol, Bs(buf) + ar * 32);
    }
  };

  f32x4 acc[4][4];
#pragma unroll
  for (int i = 0; i < 4; ++i)
#pragma unroll
    for (int jj = 0; jj < 4; ++jj) acc[i][jj] = (f32x4){0.f, 0.f, 0.f, 0.f};

  constexpr int NT = KPAD / 32;
  STAGE(0, 0);
  STAGE(1, 32);
  for (int t = 0; t < NT; ++t) {
    if (t < NT - 1) WAITV(4); else WAITV(0);   // buf t landed (t+1 may fly)
    __builtin_amdgcn_s_barrier();              // everyone's buf-t loads landed
    __builtin_amdgcn_sched_barrier(0);
    const u16* Ab = As(t % 3);
    const u16* Bb = Bs(t % 3);
    bf16x8 af[4], bfr[4];
#pragma unroll
    for (int r = 0; r < 4; ++r)
      af[r] = *(const bf16x8*)(Ab + (wm + r * 16 + fr) * 32 + fswz);
#pragma unroll
    for (int c = 0; c < 4; ++c)
      bfr[c] = *(const bf16x8*)(Bb + (wn + c * 16 + fr) * 32 + fswz);
    if (t + 2 < NT) STAGE((t + 2) % 3, (t + 2) * 32);
#pragma unroll
    for (int r = 0; r < 4; ++r)
#pragma unroll
      for (int c = 0; c < 4; ++c)
        acc[r][c] = __builtin_amdgcn_mfma_f32_16x16x32_bf16(af[r], bfr[c],
                                                            acc[r][c], 0, 0, 0);
  }

  // ---- epilogue: C tile via LDS overlay, coalesced 16B stores ----------------
  __syncthreads();                // seal all waves' staging reads (full drain)
  u16* CT = SH;                   // 128x128 u16 = 32KB of the 48KB
  const int cr = (lane >> 4) * 4;
#pragma unroll
  for (int c = 0; c < 4; ++c) {
    int col = wn + c * 16 + fr;
    float bv = HAS_BIAS ? bias[n0 + col] : 0.f;
#pragma unroll
    for (int r = 0; r < 4; ++r) {
#pragma unroll
      for (int jj = 0; jj < 4; ++jj) {
        float v = acc[r][c][jj] + bv;
        if (RELU) v = fmaxf(v, 0.f);
        CT[(wm + r * 16 + cr + jj) * 128 + col] = f32_to_bf16(v);
      }
    }
  }
  __syncthreads();
#pragma unroll
  for (int ps = 0; ps < 8; ++ps) {
    int rl = ps * 16 + (tid >> 4);
    int gm = m0 + rl;
    bf16x8 w = *(const bf16x8*)(CT + rl * 128 + (tid & 15) * 8);
    if (gm < M)
      *(bf16x8*)(Cout + (size_t)gm * OUTC + n0 + (tid & 15) * 8) = w;
  }
}

extern "C" void kernel_launch(void* const* d_in, const int* in_sizes, int n_in,
                              void* d_out, int out_size, void* d_ws,
                              size_t ws_size, hipStream_t stream) {
  const float* x  = (const float*)d_in[0];
  const int* erow = (const int*)d_in[1];
  const int* ecol = (const int*)d_in[2];
  const float* W1 = (const float*)d_in[4];
  const float* b1 = (const float*)d_in[5];
  const float* W2 = (const float*)d_in[6];
  const float* b2 = (const float*)d_in[7];
  const int E = in_sizes[1];

  char* p = (char*)d_ws;
  auto carve = [&](size_t bytes) {
    char* q = p;
    p += (bytes + 255) & ~(size_t)255;
    return q;
  };
  unsigned* xb = (unsigned*)carve((size_t)N_NODES * 160 * 4);  // 32 MB bf16 x
  unsigned* ax = (unsigned*)carve((size_t)N_NODES * 160 * 4);  // 32 MB
  unsigned* h  = (unsigned*)carve((size_t)N_NODES * 256 * 4);  // 51.2 MB
  unsigned* g2 = (unsigned*)carve((size_t)N_NODES * 256 * 4);  // 51.2 MB
  u16* W1b = (u16*)carve((size_t)HID * KP1 * 2);
  u16* W2b = (u16*)carve((size_t)OUTC * HID * 2);
  int* deg  = (int*)carve((size_t)N_NODES * 4);
  int* rs   = (int*)carve((size_t)(N_NODES + 1) * 4);
  int* cur  = (int*)carve((size_t)N_NODES * 4);
  int* csr_col = (int*)carve((size_t)E * 4);

  (void)hipMemsetAsync(deg, 0, (size_t)N_NODES * 4, stream);
  (void)hipMemsetAsync(cur, 0, (size_t)N_NODES * 4, stream);

  int eb = (E + 255) / 256;
  fused_setup<<<CX_BLK + CW1_BLK + CW2_BLK + eb, 256, 0, stream>>>(
      x, xb, W1, W1b, W2, W2b, erow, deg, E);
  k_scan<<<1, 1024, 0, stream>>>(deg, rs);
  k_scatter<<<eb, 256, 0, stream>>>(erow, ecol, E, rs, cur, csr_col);

  const int GEMM_GRID = 8 * MCHUNK * 4;   // 1568
  const size_t GEMM_LDS = 49152;          // 48KB dynamic
  // layer 1: h = relu((A @ x) @ W1^T + b1)
  spmm_x<<<N_NODES / 4, 256, 0, stream>>>((const u32x4*)xb, csr_col, rs, (u32x4*)ax);
  gemm_nt<KP1, true, true><<<GEMM_GRID, 256, GEMM_LDS, stream>>>(
      (const u16*)ax, W1b, b1, (u16*)h, N_NODES);

  // layer 2: out = normalize(A @ (h @ W2^T) + b2)
  gemm_nt<HID, false, false><<<GEMM_GRID, 256, GEMM_LDS, stream>>>(
      (const u16*)h, W2b, nullptr, (u16*)g2, N_NODES);
  spmm_norm<<<N_NODES / 4, 256, 0, stream>>>((const u32x4*)g2, csr_col, rs, b2, (float*)d_out);
}

// Round 17
// 373.900 us; speedup vs baseline: 1.1965x; 1.1588x over previous
//
#include <hip/hip_runtime.h>

#define N_NODES 50000
#define INC 300
#define KP1 320      // padded K for layer-1 GEMM (bf16)
#define HID 512
#define OUTC 512
#define MTILES 391   // ceil(50000/128)
#define MCHUNK 49    // ceil(391/8) m-tiles per XCD
#define SCAN_BLOCKS 196   // ceil(50000/256)

typedef unsigned short u16;
typedef __bf16 bf16;
typedef bf16 bf16x8 __attribute__((ext_vector_type(8)));
typedef float f32x4 __attribute__((ext_vector_type(4)));
typedef float f32x2 __attribute__((ext_vector_type(2)));
typedef unsigned u32x4 __attribute__((ext_vector_type(4)));

__device__ inline u16 f32_to_bf16(float f) {
  unsigned u = __float_as_uint(f);
  u += 0x7FFFu + ((u >> 16) & 1u);   // round-to-nearest-even
  return (u16)(u >> 16);
}

__device__ inline float bf_lo(unsigned u) { return __uint_as_float(u << 16); }
__device__ inline float bf_hi(unsigned u) { return __uint_as_float(u & 0xFFFF0000u); }

__device__ inline void gload_lds16(const void* g, void* l) {
  __builtin_amdgcn_global_load_lds(
      (const __attribute__((address_space(1))) void*)g,
      (__attribute__((address_space(3))) void*)l, 16, 0, 0);
}

// counted wait + hard scheduling fence (rule #18)
#define WAITV(N)                                            \
  do {                                                      \
    asm volatile("s_waitcnt vmcnt(" #N ")" ::: "memory");   \
    __builtin_amdgcn_sched_barrier(0);                      \
  } while (0)

__device__ __forceinline__ void acc8(float a[8], u32x4 q) {
#pragma unroll
  for (int t = 0; t < 4; ++t) {
    a[2 * t]     += bf_lo(q[t]);
    a[2 * t + 1] += bf_hi(q[t]);
  }
}

// ---- rolling-pipeline row gather: steady-state 8 dwordx4 loads in flight ----
template <int RU>
__device__ __forceinline__ void gather_row(
    const u32x4* __restrict__ src, const int* __restrict__ csr_col,
    int s, int cnt, int lane, int lanec, float a[8]) {
  const u32x4* base = src + lanec;
  for (int off = 0; off < cnt; off += 64) {
    int cnt2 = min(64, cnt - off);
    int myc = csr_col[s + off + min(lane, cnt2 - 1)];
    int ngr = (cnt2 + 3) >> 2;

    auto issue = [&](u32x4 (&q)[4], int g) {
#pragma unroll
      for (int k = 0; k < 4; ++k) {
        int c = __shfl(myc, min(4 * g + k, cnt2 - 1), 64);
        const u32x4* ap = base + (size_t)c * RU;
        asm volatile("global_load_dwordx4 %0, %1, off" : "=v"(q[k]) : "v"(ap));
      }
    };
    auto cons = [&](u32x4 (&q)[4], int g) {
#pragma unroll
      for (int k = 0; k < 4; ++k)
        if (4 * g + k < cnt2) acc8(a, q[k]);
    };

    u32x4 qa[4], qb[4];
    issue(qa, 0);
    int g = 0;
    while (g + 2 < ngr) {
      issue(qb, g + 1); WAITV(4); cons(qa, g);
      issue(qa, g + 2); WAITV(4); cons(qb, g + 1);
      g += 2;
    }
    if (g + 1 < ngr) {
      issue(qb, g + 1); WAITV(4); cons(qa, g);
      WAITV(0); cons(qb, g + 1);
    } else {
      WAITV(0); cons(qa, g);
    }
  }
}

// ---------------- fused setup: convx | convw1 | convw2 | hist ----------------
#define CX_BLK 31250                  // N_NODES*160/256
#define CW1_BLK 640                   // HID*KP1/256
#define CW2_BLK 1024                  // OUTC*HID/256
__global__ __launch_bounds__(256) void fused_setup(
    const float* __restrict__ x, unsigned* __restrict__ xb,
    const float* __restrict__ W1, u16* __restrict__ W1b,
    const float* __restrict__ W2, u16* __restrict__ W2b,
    const int* __restrict__ erow, int* __restrict__ deg, int E) {
  int bid = blockIdx.x;
  if (bid < CX_BLK) {
    int i = bid * 256 + threadIdx.x;                  // over N*160 u32 slots
    int r = i / 160, j = i - r * 160;
    unsigned out = 0;
    if (2 * j < INC) {
      f32x2 v = __builtin_nontemporal_load((const f32x2*)(x + (size_t)r * INC + 2 * j));
      out = (unsigned)f32_to_bf16(v.x) | ((unsigned)f32_to_bf16(v.y) << 16);
    }
    xb[i] = out;
  } else if (bid < CX_BLK + CW1_BLK) {
    int i = (bid - CX_BLK) * 256 + threadIdx.x;       // over HID*KP1
    int r = i / KP1, k = i - r * KP1;
    W1b[i] = (k < INC) ? f32_to_bf16(W1[(size_t)r * INC + k]) : (u16)0;
  } else if (bid < CX_BLK + CW1_BLK + CW2_BLK) {
    int i = (bid - CX_BLK - CW1_BLK) * 256 + threadIdx.x;   // over OUTC*HID
    W2b[i] = f32_to_bf16(W2[i]);
  } else {
    int i = (bid - CX_BLK - CW1_BLK - CW2_BLK) * 256 + threadIdx.x;
    if (i < E) atomicAdd(&deg[erow[i]], 1);
  }
}

// ---------------- CSR multi-block scan (3 tiny kernels) ----------------------
__global__ __launch_bounds__(256) void k_scan1(const int* __restrict__ deg,
                                               int* __restrict__ bsum) {
  int i = blockIdx.x * 256 + threadIdx.x;
  int v = (i < N_NODES) ? deg[i] : 0;
#pragma unroll
  for (int off = 32; off > 0; off >>= 1) v += __shfl_down(v, off, 64);
  __shared__ int ws[4];
  if ((threadIdx.x & 63) == 0) ws[threadIdx.x >> 6] = v;
  __syncthreads();
  if (threadIdx.x == 0) bsum[blockIdx.x] = ws[0] + ws[1] + ws[2] + ws[3];
}

__global__ __launch_bounds__(256) void k_scan2(const int* __restrict__ bsum,
                                               int* __restrict__ boff,
                                               int* __restrict__ rowstart) {
  int tid = threadIdx.x;
  int lane = tid & 63, w = tid >> 6;
  int v = (tid < SCAN_BLOCKS) ? bsum[tid] : 0;
  int x = v;
#pragma unroll
  for (int off = 1; off < 64; off <<= 1) {
    int y = __shfl_up(x, off, 64);
    if (lane >= off) x += y;
  }
  __shared__ int wsum[4];
  if (lane == 63) wsum[w] = x;
  __syncthreads();
  int add = 0;
  for (int k = 0; k < w; ++k) add += wsum[k];
  x += add;
  if (tid < SCAN_BLOCKS) boff[tid] = x - v;       // exclusive
  if (tid == 255) rowstart[N_NODES] = wsum[0] + wsum[1] + wsum[2] + wsum[3];
}

__global__ __launch_bounds__(256) void k_scan3(const int* __restrict__ deg,
                                               const int* __restrict__ boff,
                                               int* __restrict__ rowstart) {
  int i = blockIdx.x * 256 + threadIdx.x;
  int v = (i < N_NODES) ? deg[i] : 0;
  int lane = threadIdx.x & 63, w = threadIdx.x >> 6;
  int x = v;
#pragma unroll
  for (int off = 1; off < 64; off <<= 1) {
    int y = __shfl_up(x, off, 64);
    if (lane >= off) x += y;
  }
  __shared__ int wsum[4];
  if (lane == 63) wsum[w] = x;
  __syncthreads();
  int add = boff[blockIdx.x];
  for (int k = 0; k < w; ++k) add += wsum[k];
  if (i < N_NODES) rowstart[i] = x - v + add;     // exclusive prefix
}

__global__ void k_scatter(const int* __restrict__ erow, const int* __restrict__ ecol,
                          int E, const int* __restrict__ rowstart,
                          int* __restrict__ cursor, int* __restrict__ csr_col) {
  int i = blockIdx.x * blockDim.x + threadIdx.x;
  if (i < E) {
    int r = erow[i];
    int p = atomicAdd(&cursor[r], 1);
    csr_col[rowstart[r] + p] = ecol[i];
  }
}

// ---------------- SpMM layer 1: ax = (A @ xb) * 1/deg ------------------------
__global__ __launch_bounds__(256, 8) void spmm_x(
    const u32x4* __restrict__ xb, const int* __restrict__ csr_col,
    const int* __restrict__ rs, u32x4* __restrict__ ax) {
  int r = blockIdx.x * 4 + (threadIdx.x >> 6);
  int lane = threadIdx.x & 63;
  int lanec = min(lane, 39);               // row = 160 u32 = 40 x u32x4
  int s = rs[r], e = rs[r + 1];
  float a[8];
#pragma unroll
  for (int k = 0; k < 8; ++k) a[k] = 0.f;
  gather_row<40>(xb, csr_col, s, e - s, lane, lanec, a);
  float inv = 1.0f / (float)max(e - s, 1);
  u32x4 o;
#pragma unroll
  for (int j = 0; j < 4; ++j) {
    unsigned lo = f32_to_bf16(a[2 * j] * inv);
    unsigned hi = f32_to_bf16(a[2 * j + 1] * inv);
    o[j] = lo | (hi << 16);
  }
  if (lane < 40) ax[(size_t)r * 40 + lane] = o;
}

// ---- SpMM layer 2 fused: out = normalize( (A @ g) * 1/deg + b2 ) -------------
__global__ __launch_bounds__(256, 8) void spmm_norm(
    const u32x4* __restrict__ g, const int* __restrict__ csr_col,
    const int* __restrict__ rs, const float* __restrict__ b2,
    float* __restrict__ out) {
  int r = blockIdx.x * 4 + (threadIdx.x >> 6);
  int lane = threadIdx.x & 63;
  int s = rs[r], e = rs[r + 1];
  float a[8];
#pragma unroll
  for (int k = 0; k < 8; ++k) a[k] = 0.f;
  gather_row<64>(g, csr_col, s, e - s, lane, lane, a);
  float inv = 1.0f / (float)max(e - s, 1);
  f32x4 bv0 = *(const f32x4*)(b2 + lane * 8);
  f32x4 bv1 = *(const f32x4*)(b2 + lane * 8 + 4);
  float v[8];
  v[0] = a[0] * inv + bv0.x; v[1] = a[1] * inv + bv0.y;
  v[2] = a[2] * inv + bv0.z; v[3] = a[3] * inv + bv0.w;
  v[4] = a[4] * inv + bv1.x; v[5] = a[5] * inv + bv1.y;
  v[6] = a[6] * inv + bv1.z; v[7] = a[7] * inv + bv1.w;
  float ss = 0.f;
#pragma unroll
  for (int k = 0; k < 8; ++k) ss += v[k] * v[k];
#pragma unroll
  for (int off = 32; off > 0; off >>= 1) ss += __shfl_xor(ss, off, 64);
  float innrm = 1.0f / fmaxf(sqrtf(ss), 1e-12f);
  f32x4 o0 = {v[0] * innrm, v[1] * innrm, v[2] * innrm, v[3] * innrm};
  f32x4 o1 = {v[4] * innrm, v[5] * innrm, v[6] * innrm, v[7] * innrm};
  float* op = out + (size_t)r * OUTC + lane * 8;
  __builtin_nontemporal_store(o0, (f32x4*)op);
  __builtin_nontemporal_store(o1, (f32x4*)(op + 4));
}

// ---- bf16 MFMA GEMM: 3-buffer counted-vmcnt gload_lds loop + T2 swizzle +
//      LDS-staged coalesced epilogue with nontemporal C stores.
template <int KPAD, bool RELU, bool HAS_BIAS>
__global__ __launch_bounds__(256) void gemm_nt(
    const u16* __restrict__ A, const u16* __restrict__ B,
    const float* __restrict__ bias, u16* __restrict__ Cout, int M) {
  extern __shared__ __align__(16) u16 SH[];   // 48KB: 3x(A 8KB + B 8KB)
  const int bid = blockIdx.x;
  const int xcd = bid & 7;
  const int j = bid >> 3;
  const int mt = xcd * MCHUNK + (j >> 2);
  if (mt >= MTILES) return;
  const int m0 = mt * 128;
  const int n0 = (j & 3) * 128;

  const int tid = threadIdx.x;
  const int wid = tid >> 6;
  const int lane = tid & 63;

  const int srow = lane >> 2;
  // write-side swizzle: lane's linear LDS slot (lane&3) receives global slot
  // (lane&3) ^ f(row),  f(row) = (srow>>1)&3 = (lane>>3)&3
  const int scol = (((lane & 3) ^ ((lane >> 3) & 3)) * 8);
  const int wm = (wid >> 1) * 64;
  const int wn = (wid & 1) * 64;
  const int fr = lane & 15;
  // read-side: global slot q lives at stored slot q ^ ((fr>>1)&3)
  const int fswz = (((lane >> 4) ^ ((fr >> 1) & 3)) * 8);

  auto As = [&](int buf) { return SH + buf * 4096; };
  auto Bs = [&](int buf) { return SH + 12288 + buf * 4096; };

  auto STAGE = [&](int buf, int k0) {       // 4 gload_lds per thread
#pragma unroll
    for (int i = 0; i < 2; ++i) {
      int ar = wid * 32 + i * 16;
      int gm = m0 + ar + srow;
      if (gm >= M) gm = M - 1;
      gload_lds16(A + (size_t)gm * KPAD + k0 + scol, As(buf) + ar * 32);
      int gn = n0 + ar + srow;
      gload_lds16(B + (size_t)gn * KPAD + k0 + scol, Bs(buf) + ar * 32);
    }
  };

  f32x4 acc[4][4];
#pragma unroll
  for (int i = 0; i < 4; ++i)
#pragma unroll
    for (int jj = 0; jj < 4; ++jj) acc[i][jj] = (f32x4){0.f, 0.f, 0.f, 0.f};

  constexpr int NT = KPAD / 32;
  STAGE(0, 0);
  STAGE(1, 32);
  for (int t = 0; t < NT; ++t) {
    if (t < NT - 1) WAITV(4); else WAITV(0);   // buf t landed (t+1 may fly)
    __builtin_amdgcn_s_barrier();              // everyone's buf-t loads landed
    __builtin_amdgcn_sched_barrier(0);
    const u16* Ab = As(t % 3);
    const u16* Bb = Bs(t % 3);
    bf16x8 af[4], bfr[4];
#pragma unroll
    for (int r = 0; r < 4; ++r)
      af[r] = *(const bf16x8*)(Ab + (wm + r * 16 + fr) * 32 + fswz);
#pragma unroll
    for (int c = 0; c < 4; ++c)
      bfr[c] = *(const bf16x8*)(Bb + (wn + c * 16 + fr) * 32 + fswz);
    if (t + 2 < NT) STAGE((t + 2) % 3, (t + 2) * 32);
#pragma unroll
    for (int r = 0; r < 4; ++r)
#pragma unroll
      for (int c = 0; c < 4; ++c)
        acc[r][c] = __builtin_amdgcn_mfma_f32_16x16x32_bf16(af[r], bfr[c],
                                                            acc[r][c], 0, 0, 0);
  }

  // ---- epilogue: C tile via LDS overlay, coalesced nt 16B stores -------------
  __syncthreads();                // seal all waves' staging reads (full drain)
  u16* CT = SH;                   // 128x128 u16 = 32KB of the 48KB
  const int cr = (lane >> 4) * 4;
#pragma unroll
  for (int c = 0; c < 4; ++c) {
    int col = wn + c * 16 + fr;
    float bv = HAS_BIAS ? bias[n0 + col] : 0.f;
#pragma unroll
    for (int r = 0; r < 4; ++r) {
#pragma unroll
      for (int jj = 0; jj < 4; ++jj) {
        float v = acc[r][c][jj] + bv;
        if (RELU) v = fmaxf(v, 0.f);
        CT[(wm + r * 16 + cr + jj) * 128 + col] = f32_to_bf16(v);
      }
    }
  }
  __syncthreads();
#pragma unroll
  for (int ps = 0; ps < 8; ++ps) {
    int rl = ps * 16 + (tid >> 4);
    int gm = m0 + rl;
    u32x4 w = *(const u32x4*)(CT + rl * 128 + (tid & 15) * 8);
    if (gm < M)
      __builtin_nontemporal_store(
          w, (u32x4*)(Cout + (size_t)gm * OUTC + n0 + (tid & 15) * 8));
  }
}

extern "C" void kernel_launch(void* const* d_in, const int* in_sizes, int n_in,
                              void* d_out, int out_size, void* d_ws,
                              size_t ws_size, hipStream_t stream) {
  const float* x  = (const float*)d_in[0];
  const int* erow = (const int*)d_in[1];
  const int* ecol = (const int*)d_in[2];
  const float* W1 = (const float*)d_in[4];
  const float* b1 = (const float*)d_in[5];
  const float* W2 = (const float*)d_in[6];
  const float* b2 = (const float*)d_in[7];
  const int E = in_sizes[1];

  char* p = (char*)d_ws;
  auto carve = [&](size_t bytes) {
    char* q = p;
    p += (bytes + 255) & ~(size_t)255;
    return q;
  };
  unsigned* xb = (unsigned*)carve((size_t)N_NODES * 160 * 4);  // 32 MB bf16 x
  unsigned* ax = (unsigned*)carve((size_t)N_NODES * 160 * 4);  // 32 MB
  unsigned* h  = (unsigned*)carve((size_t)N_NODES * 256 * 4);  // 51.2 MB
  unsigned* g2 = (unsigned*)carve((size_t)N_NODES * 256 * 4);  // 51.2 MB
  u16* W1b = (u16*)carve((size_t)HID * KP1 * 2);
  u16* W2b = (u16*)carve((size_t)OUTC * HID * 2);
  int* deg  = (int*)carve((size_t)N_NODES * 4);
  int* rs   = (int*)carve((size_t)(N_NODES + 1) * 4);
  int* cur  = (int*)carve((size_t)N_NODES * 4);
  int* csr_col = (int*)carve((size_t)E * 4);
  int* bsum = (int*)carve((size_t)SCAN_BLOCKS * 4);
  int* boff = (int*)carve((size_t)SCAN_BLOCKS * 4);

  (void)hipMemsetAsync(deg, 0, (size_t)N_NODES * 4, stream);
  (void)hipMemsetAsync(cur, 0, (size_t)N_NODES * 4, stream);

  int eb = (E + 255) / 256;
  fused_setup<<<CX_BLK + CW1_BLK + CW2_BLK + eb, 256, 0, stream>>>(
      x, xb, W1, W1b, W2, W2b, erow, deg, E);
  k_scan1<<<SCAN_BLOCKS, 256, 0, stream>>>(deg, bsum);
  k_scan2<<<1, 256, 0, stream>>>(bsum, boff, rs);
  k_scan3<<<SCAN_BLOCKS, 256, 0, stream>>>(deg, boff, rs);
  k_scatter<<<eb, 256, 0, stream>>>(erow, ecol, E, rs, cur, csr_col);

  const int GEMM_GRID = 8 * MCHUNK * 4;   // 1568
  const size_t GEMM_LDS = 49152;          // 48KB dynamic
  // layer 1: h = relu((A @ x) @ W1^T + b1)
  spmm_x<<<N_NODES / 4, 256, 0, stream>>>((const u32x4*)xb, csr_col, rs, (u32x4*)ax);
  gemm_nt<KP1, true, true><<<GEMM_GRID, 256, GEMM_LDS, stream>>>(
      (const u16*)ax, W1b, b1, (u16*)h, N_NODES);

  // layer 2: out = normalize(A @ (h @ W2^T) + b2)
  gemm_nt<HID, false, false><<<GEMM_GRID, 256, GEMM_LDS, stream>>>(
      (const u16*)h, W2b, nullptr, (u16*)g2, N_NODES);
  spmm_norm<<<N_NODES / 4, 256, 0, stream>>>((const u32x4*)g2, csr_col, rs, b2, (float*)d_out);
}